// Round 1
// baseline (706.586 us; speedup 1.0000x reference)
//
#include <hip/hip_runtime.h>

#define N_NODES 50000
#define N_EDGES 800000
#define F_INN   128
#define F_HID   96
#define F_OUTT  40

// ---------------------------------------------------------------------------
// CSR build: counts -> scan(+dinv) -> fill
// ---------------------------------------------------------------------------

__global__ void zero_counts_kernel(int* __restrict__ counts, int n) {
    int i = blockIdx.x * blockDim.x + threadIdx.x;
    if (i < n) counts[i] = 0;
}

__global__ void count_kernel(const int* __restrict__ dst, int* __restrict__ counts, int e) {
    int i = blockIdx.x * blockDim.x + threadIdx.x;
    if (i < e) atomicAdd(&counts[dst[i]], 1);
}

// Single-block exclusive scan over counts[0..n), also emits cursor copy and
// dinv[i] = rsqrt(counts[i] + 1)  (+1 = self loop).
__global__ __launch_bounds__(1024) void scan_kernel(
        const int* __restrict__ counts, int* __restrict__ row_start,
        int* __restrict__ cursor, float* __restrict__ dinv, int n) {
    __shared__ int wave_sums[16];
    __shared__ int s_carry;
    int tid  = threadIdx.x;
    int lane = tid & 63;
    int wid  = tid >> 6;
    if (tid == 0) s_carry = 0;
    __syncthreads();
    for (int base = 0; base < n; base += 1024) {
        int i = base + tid;
        int v = (i < n) ? counts[i] : 0;
        int val = v;
        // inclusive wave scan (64 lanes)
        #pragma unroll
        for (int off = 1; off < 64; off <<= 1) {
            int u = __shfl_up(val, off, 64);
            if (lane >= off) val += u;
        }
        if (lane == 63) wave_sums[wid] = val;
        __syncthreads();
        if (wid == 0) {
            int w = (lane < 16) ? wave_sums[lane] : 0;
            #pragma unroll
            for (int off = 1; off < 16; off <<= 1) {
                int u = __shfl_up(w, off, 64);
                if (lane >= off) w += u;
            }
            if (lane < 16) wave_sums[lane] = w;  // inclusive wave totals
        }
        __syncthreads();
        int wave_excl = (wid == 0) ? 0 : wave_sums[wid - 1];
        int excl = s_carry + wave_excl + (val - v);
        if (i < n) {
            row_start[i] = excl;
            cursor[i]    = excl;
            dinv[i]      = rsqrtf((float)(v + 1));
        }
        __syncthreads();                      // everyone consumed old s_carry
        if (tid == 0) s_carry += wave_sums[15];
        __syncthreads();
    }
    if (tid == 0) row_start[n] = s_carry;     // == E
}

__global__ void fill_csr_kernel(const int* __restrict__ src, const int* __restrict__ dst,
                                int* __restrict__ cursor, const float* __restrict__ dinv,
                                int* __restrict__ csr_src, float* __restrict__ csr_w, int e) {
    int i = blockIdx.x * blockDim.x + threadIdx.x;
    if (i >= e) return;
    int s = src[i], d = dst[i];
    int pos = atomicAdd(&cursor[d], 1);
    csr_src[pos] = s;
    csr_w[pos]   = dinv[s] * dinv[d];
}

// ---------------------------------------------------------------------------
// Dense GEMM: C[n x FO] = A[n x FI] @ W[FI x FO]   (fp32, VALU; W in LDS)
// ---------------------------------------------------------------------------

template <int FI, int FO>
__global__ __launch_bounds__(256) void gemm_kernel(
        const float* __restrict__ A, const float* __restrict__ W,
        float* __restrict__ C, int n) {
    __shared__ float Wlds[FI * FO];
    for (int i = threadIdx.x; i < FI * FO; i += 256) Wlds[i] = W[i];
    __syncthreads();
    int idx = blockIdx.x * 256 + threadIdx.x;
    if (idx >= n * FO) return;
    int node = idx / FO;
    int j    = idx - node * FO;
    const float* a = A + node * FI;
    float acc = 0.f;
    #pragma unroll
    for (int k = 0; k < FI; k += 4) {
        float4 av = *reinterpret_cast<const float4*>(a + k);
        acc += av.x * Wlds[(k + 0) * FO + j];
        acc += av.y * Wlds[(k + 1) * FO + j];
        acc += av.z * Wlds[(k + 2) * FO + j];
        acc += av.w * Wlds[(k + 3) * FO + j];
    }
    C[idx] = acc;
}

template <int FI, int FO>
__global__ __launch_bounds__(256) void gemm_bias_kernel(
        const float* __restrict__ A, const float* __restrict__ W,
        const float* __restrict__ bias, float* __restrict__ C, int n) {
    __shared__ float Wlds[FI * FO];
    for (int i = threadIdx.x; i < FI * FO; i += 256) Wlds[i] = W[i];
    __syncthreads();
    int idx = blockIdx.x * 256 + threadIdx.x;
    if (idx >= n * FO) return;
    int node = idx / FO;
    int j    = idx - node * FO;
    const float* a = A + node * FI;
    float acc = 0.f;
    #pragma unroll
    for (int k = 0; k < FI; k += 4) {
        float4 av = *reinterpret_cast<const float4*>(a + k);
        acc += av.x * Wlds[(k + 0) * FO + j];
        acc += av.y * Wlds[(k + 1) * FO + j];
        acc += av.z * Wlds[(k + 2) * FO + j];
        acc += av.w * Wlds[(k + 3) * FO + j];
    }
    C[idx] = acc + bias[j];
}

// ---------------------------------------------------------------------------
// Fused aggregation: H[n][f] = relu( b[f] + dinv[n]^2 * T[n][f]
//                                    + sum_{e in CSR row n} w_e * T[src_e][f] )
// blockDim = (96, 4): 96 feature lanes x 4 nodes per block.
// ---------------------------------------------------------------------------

__global__ __launch_bounds__(384) void agg_kernel(
        const float* __restrict__ T, const int* __restrict__ row_start,
        const int* __restrict__ csr_src, const float* __restrict__ csr_w,
        const float* __restrict__ dinv, const float* __restrict__ bias,
        float* __restrict__ H, int n) {
    int f    = threadIdx.x;                       // 0..95
    int node = blockIdx.x * 4 + threadIdx.y;
    if (node >= n) return;
    float dn  = dinv[node];
    float acc = T[node * F_HID + f] * dn * dn;    // self loop
    int beg = row_start[node];
    int end = row_start[node + 1];
    for (int idx = beg; idx < end; ++idx) {
        int   s = csr_src[idx];                   // wave-uniform broadcast
        float w = csr_w[idx];
        acc += T[s * F_HID + f] * w;              // coalesced 384B row gather
    }
    H[node * F_HID + f] = fmaxf(acc + bias[f], 0.f);
}

// ---------------------------------------------------------------------------

extern "C" void kernel_launch(void* const* d_in, const int* in_sizes, int n_in,
                              void* d_out, int out_size, void* d_ws, size_t ws_size,
                              hipStream_t stream) {
    const float* x    = (const float*)d_in[0];
    const int*   ei   = (const int*)d_in[1];
    const float* W1   = (const float*)d_in[2];
    const float* b1   = (const float*)d_in[3];
    const float* W2   = (const float*)d_in[4];
    const float* b2   = (const float*)d_in[5];
    const float* Wout = (const float*)d_in[6];
    const float* bout = (const float*)d_in[7];
    float*       out  = (float*)d_out;

    const int* src = ei;            // edge_index[0]
    const int* dst = ei + N_EDGES;  // edge_index[1]

    // Workspace layout (512B-aligned slabs)
    char* ws = (char*)d_ws;
    size_t off = 0;
    auto alloc = [&](size_t bytes) {
        size_t o = off;
        off = (off + bytes + 511) & ~(size_t)511;
        return (void*)(ws + o);
    };
    int*   counts    = (int*)  alloc(N_NODES * sizeof(int));
    int*   cursor    = (int*)  alloc(N_NODES * sizeof(int));
    int*   row_start = (int*)  alloc((N_NODES + 1) * sizeof(int));
    float* dinv      = (float*)alloc(N_NODES * sizeof(float));
    int*   csr_src   = (int*)  alloc(N_EDGES * sizeof(int));
    float* csr_w     = (float*)alloc(N_EDGES * sizeof(float));
    float* bufA      = (float*)alloc((size_t)N_NODES * F_HID * sizeof(float));
    float* bufB      = (float*)alloc((size_t)N_NODES * F_HID * sizeof(float));

    // --- CSR build (topology only, reused by both layers) ---
    zero_counts_kernel<<<(N_NODES + 255) / 256, 256, 0, stream>>>(counts, N_NODES);
    count_kernel<<<(N_EDGES + 255) / 256, 256, 0, stream>>>(dst, counts, N_EDGES);
    scan_kernel<<<1, 1024, 0, stream>>>(counts, row_start, cursor, dinv, N_NODES);
    fill_csr_kernel<<<(N_EDGES + 255) / 256, 256, 0, stream>>>(
        src, dst, cursor, dinv, csr_src, csr_w, N_EDGES);

    // --- Layer 1: t1 = x @ W1; h1 = relu(agg(t1) + b1) ---
    gemm_kernel<F_INN, F_HID><<<(N_NODES * F_HID + 255) / 256, 256, 0, stream>>>(
        x, W1, bufA, N_NODES);
    agg_kernel<<<(N_NODES + 3) / 4, dim3(F_HID, 4), 0, stream>>>(
        bufA, row_start, csr_src, csr_w, dinv, b1, bufB, N_NODES);

    // --- Layer 2: t2 = h1 @ W2; h2 = relu(agg(t2) + b2) ---
    gemm_kernel<F_HID, F_HID><<<(N_NODES * F_HID + 255) / 256, 256, 0, stream>>>(
        bufB, W2, bufA, N_NODES);
    agg_kernel<<<(N_NODES + 3) / 4, dim3(F_HID, 4), 0, stream>>>(
        bufA, row_start, csr_src, csr_w, dinv, b2, bufB, N_NODES);

    // --- Output: out = h2 @ Wout + bout ---
    gemm_bias_kernel<F_HID, F_OUTT><<<(N_NODES * F_OUTT + 255) / 256, 256, 0, stream>>>(
        bufB, Wout, bout, out, N_NODES);
}

// Round 2
// 329.106 us; speedup vs baseline: 2.1470x; 2.1470x over previous
//
#include <hip/hip_runtime.h>

#define N_NODES 50000
#define N_EDGES 800000
#define F_INN   128
#define F_HID   96
#define F_OUTT  40

// ---------------------------------------------------------------------------
// CSR build: counts -> 3-phase parallel scan (+dinv) -> fill (packed int2)
// ---------------------------------------------------------------------------

__global__ void count_kernel(const int* __restrict__ dst, int* __restrict__ counts, int e) {
    int i = blockIdx.x * blockDim.x + threadIdx.x;
    if (i < e) atomicAdd(&counts[dst[i]], 1);
}

// Phase 1: per-block (1024-wide) exclusive scan; write local scan + dinv + block sum.
__global__ __launch_bounds__(1024) void scan_local_kernel(
        const int* __restrict__ counts, int* __restrict__ row_start,
        float* __restrict__ dinv, int* __restrict__ blk_sums, int n) {
    __shared__ int wave_sums[16];
    int tid = threadIdx.x, lane = tid & 63, wid = tid >> 6;
    int i = blockIdx.x * 1024 + tid;
    int v = (i < n) ? counts[i] : 0;
    int val = v;
    #pragma unroll
    for (int off = 1; off < 64; off <<= 1) {
        int u = __shfl_up(val, off, 64);
        if (lane >= off) val += u;
    }
    if (lane == 63) wave_sums[wid] = val;
    __syncthreads();
    if (wid == 0) {
        int w = (lane < 16) ? wave_sums[lane] : 0;
        #pragma unroll
        for (int off = 1; off < 16; off <<= 1) {
            int u = __shfl_up(w, off, 64);
            if (lane >= off) w += u;
        }
        if (lane < 16) wave_sums[lane] = w;   // inclusive wave totals
    }
    __syncthreads();
    int excl = ((wid == 0) ? 0 : wave_sums[wid - 1]) + (val - v);
    if (i < n) {
        row_start[i] = excl;                  // local (no global offset yet)
        dinv[i] = rsqrtf((float)(v + 1));     // +1 self loop
    }
    if (tid == 0) blk_sums[blockIdx.x] = wave_sums[15];
}

// Phase 2: one wave scans <=64 block sums -> exclusive offsets; writes total.
__global__ void scan_blk_kernel(const int* __restrict__ blk_sums, int* __restrict__ blk_off,
                                int* __restrict__ row_start, int n, int nblk) {
    int lane = threadIdx.x;
    int v = (lane < nblk) ? blk_sums[lane] : 0;
    int val = v;
    #pragma unroll
    for (int off = 1; off < 64; off <<= 1) {
        int u = __shfl_up(val, off, 64);
        if (lane >= off) val += u;
    }
    if (lane < nblk) blk_off[lane] = val - v;
    if (lane == 63) row_start[n] = val;       // == E
}

// Phase 3: add block offset; emit cursor copy.
__global__ __launch_bounds__(1024) void scan_apply_kernel(
        int* __restrict__ row_start, int* __restrict__ cursor,
        const int* __restrict__ blk_off, int n) {
    int i = blockIdx.x * 1024 + threadIdx.x;
    if (i >= n) return;
    int v = row_start[i] + blk_off[blockIdx.x];
    row_start[i] = v;
    cursor[i] = v;
}

__global__ void fill_csr_kernel(const int* __restrict__ src, const int* __restrict__ dst,
                                int* __restrict__ cursor, const float* __restrict__ dinv,
                                int2* __restrict__ csr, int e) {
    int i = blockIdx.x * blockDim.x + threadIdx.x;
    if (i >= e) return;
    int s = src[i], d = dst[i];
    int pos = atomicAdd(&cursor[d], 1);
    csr[pos] = make_int2(s, __float_as_int(dinv[s] * dinv[d]));
}

// ---------------------------------------------------------------------------
// GEMM: C[n x 96] = A[n x FI] @ W[FI x 96].  blockDim (24,16): thread = 4 j x
// 4 nodes (strided 16). W in LDS read as b128, reused across 4 nodes.
// ---------------------------------------------------------------------------

template <int FI>
__global__ __launch_bounds__(384) void gemm96_kernel(
        const float* __restrict__ A, const float* __restrict__ W,
        float* __restrict__ C, int n) {
    __shared__ float Wlds[FI * 96];
    int tid = threadIdx.y * 24 + threadIdx.x;
    for (int i = tid; i < FI * 24; i += 384)
        reinterpret_cast<float4*>(Wlds)[i] = reinterpret_cast<const float4*>(W)[i];
    __syncthreads();

    int j  = threadIdx.x * 4;                 // 0..92
    int n0 = blockIdx.x * 64 + threadIdx.y;   // nodes n0, +16, +32, +48
    int nn[4];
    #pragma unroll
    for (int t = 0; t < 4; ++t) nn[t] = min(n0 + 16 * t, n - 1);

    float4 acc[4];
    #pragma unroll
    for (int t = 0; t < 4; ++t) acc[t] = make_float4(0.f, 0.f, 0.f, 0.f);

    for (int k = 0; k < FI; k += 4) {
        float4 a[4];
        #pragma unroll
        for (int t = 0; t < 4; ++t)
            a[t] = *reinterpret_cast<const float4*>(A + (size_t)nn[t] * FI + k);
        float4 w0 = *reinterpret_cast<const float4*>(Wlds + (k + 0) * 96 + j);
        float4 w1 = *reinterpret_cast<const float4*>(Wlds + (k + 1) * 96 + j);
        float4 w2 = *reinterpret_cast<const float4*>(Wlds + (k + 2) * 96 + j);
        float4 w3 = *reinterpret_cast<const float4*>(Wlds + (k + 3) * 96 + j);
        #pragma unroll
        for (int t = 0; t < 4; ++t) {
            acc[t].x += a[t].x * w0.x + a[t].y * w1.x + a[t].z * w2.x + a[t].w * w3.x;
            acc[t].y += a[t].x * w0.y + a[t].y * w1.y + a[t].z * w2.y + a[t].w * w3.y;
            acc[t].z += a[t].x * w0.z + a[t].y * w1.z + a[t].z * w2.z + a[t].w * w3.z;
            acc[t].w += a[t].x * w0.w + a[t].y * w1.w + a[t].z * w2.w + a[t].w * w3.w;
        }
    }
    #pragma unroll
    for (int t = 0; t < 4; ++t) {
        int node = n0 + 16 * t;
        if (node < n)
            *reinterpret_cast<float4*>(C + (size_t)node * 96 + j) = acc[t];
    }
}

// Output GEMM: out[n x 40] = A[n x 96] @ W[96 x 40] + bias. blockDim (10,32).
__global__ __launch_bounds__(320) void gemm_out_kernel(
        const float* __restrict__ A, const float* __restrict__ W,
        const float* __restrict__ bias, float* __restrict__ C, int n) {
    __shared__ float Wlds[96 * 40];
    int tid = threadIdx.y * 10 + threadIdx.x;
    for (int i = tid; i < 96 * 10; i += 320)
        reinterpret_cast<float4*>(Wlds)[i] = reinterpret_cast<const float4*>(W)[i];
    __syncthreads();

    int j    = threadIdx.x * 4;               // 0..36
    int node = blockIdx.x * 32 + threadIdx.y;
    int nc   = min(node, n - 1);
    float4 acc = make_float4(0.f, 0.f, 0.f, 0.f);
    for (int k = 0; k < 96; k += 4) {
        float4 a = *reinterpret_cast<const float4*>(A + (size_t)nc * 96 + k);
        float4 w0 = *reinterpret_cast<const float4*>(Wlds + (k + 0) * 40 + j);
        float4 w1 = *reinterpret_cast<const float4*>(Wlds + (k + 1) * 40 + j);
        float4 w2 = *reinterpret_cast<const float4*>(Wlds + (k + 2) * 40 + j);
        float4 w3 = *reinterpret_cast<const float4*>(Wlds + (k + 3) * 40 + j);
        acc.x += a.x * w0.x + a.y * w1.x + a.z * w2.x + a.w * w3.x;
        acc.y += a.x * w0.y + a.y * w1.y + a.z * w2.y + a.w * w3.y;
        acc.z += a.x * w0.z + a.y * w1.z + a.z * w2.z + a.w * w3.z;
        acc.w += a.x * w0.w + a.y * w1.w + a.z * w2.w + a.w * w3.w;
    }
    if (node < n) {
        float4 b = *reinterpret_cast<const float4*>(bias + j);
        acc.x += b.x; acc.y += b.y; acc.z += b.z; acc.w += b.w;
        *reinterpret_cast<float4*>(C + (size_t)node * 40 + j) = acc;
    }
}

// ---------------------------------------------------------------------------
// Aggregation: one WAVE per node. Lanes 0..47 hold float2 of the 96-float row.
// Edge metadata is wave-uniform (scalar loads); edge loop unrolled x4 so 4
// row-gathers are in flight.
// ---------------------------------------------------------------------------

__global__ __launch_bounds__(256) void agg_kernel(
        const float* __restrict__ T, const int* __restrict__ row_start,
        const int2* __restrict__ csr, const float* __restrict__ dinv,
        const float* __restrict__ bias, float* __restrict__ H, int n) {
    int lane = threadIdx.x & 63;
    int node = __builtin_amdgcn_readfirstlane(blockIdx.x * 4 + (threadIdx.x >> 6));
    if (node >= n) return;
    int fl = min(lane, 47);                    // lanes 48..63 duplicate lane 47
    const float2* Tc = reinterpret_cast<const float2*>(T);   // row stride 48

    float dn = dinv[node];
    float2 t = Tc[node * 48 + fl];
    float2 acc;
    acc.x = t.x * dn * dn;                     // self loop
    acc.y = t.y * dn * dn;

    int idx = row_start[node];
    int end = row_start[node + 1];
    for (; idx + 4 <= end; idx += 4) {
        int2 e0 = csr[idx + 0];
        int2 e1 = csr[idx + 1];
        int2 e2 = csr[idx + 2];
        int2 e3 = csr[idx + 3];
        float2 t0 = Tc[e0.x * 48 + fl];
        float2 t1 = Tc[e1.x * 48 + fl];
        float2 t2 = Tc[e2.x * 48 + fl];
        float2 t3 = Tc[e3.x * 48 + fl];
        float w0 = __int_as_float(e0.y), w1 = __int_as_float(e1.y);
        float w2 = __int_as_float(e2.y), w3 = __int_as_float(e3.y);
        acc.x += t0.x * w0; acc.y += t0.y * w0;
        acc.x += t1.x * w1; acc.y += t1.y * w1;
        acc.x += t2.x * w2; acc.y += t2.y * w2;
        acc.x += t3.x * w3; acc.y += t3.y * w3;
    }
    for (; idx < end; ++idx) {
        int2 e = csr[idx];
        float2 tt = Tc[e.x * 48 + fl];
        float w = __int_as_float(e.y);
        acc.x += tt.x * w; acc.y += tt.y * w;
    }
    if (lane < 48) {
        float2 b = reinterpret_cast<const float2*>(bias)[lane];
        float2 o;
        o.x = fmaxf(acc.x + b.x, 0.f);
        o.y = fmaxf(acc.y + b.y, 0.f);
        reinterpret_cast<float2*>(H)[node * 48 + lane] = o;
    }
}

// ---------------------------------------------------------------------------

extern "C" void kernel_launch(void* const* d_in, const int* in_sizes, int n_in,
                              void* d_out, int out_size, void* d_ws, size_t ws_size,
                              hipStream_t stream) {
    const float* x    = (const float*)d_in[0];
    const int*   ei   = (const int*)d_in[1];
    const float* W1   = (const float*)d_in[2];
    const float* b1   = (const float*)d_in[3];
    const float* W2   = (const float*)d_in[4];
    const float* b2   = (const float*)d_in[5];
    const float* Wout = (const float*)d_in[6];
    const float* bout = (const float*)d_in[7];
    float*       out  = (float*)d_out;

    const int* src = ei;            // edge_index[0]
    const int* dst = ei + N_EDGES;  // edge_index[1]

    char* ws = (char*)d_ws;
    size_t off = 0;
    auto alloc = [&](size_t bytes) {
        size_t o = off;
        off = (off + bytes + 511) & ~(size_t)511;
        return (void*)(ws + o);
    };
    int*   counts    = (int*)  alloc(N_NODES * sizeof(int));
    int*   cursor    = (int*)  alloc(N_NODES * sizeof(int));
    int*   row_start = (int*)  alloc((N_NODES + 1) * sizeof(int));
    float* dinv      = (float*)alloc(N_NODES * sizeof(float));
    int*   blk_sums  = (int*)  alloc(64 * sizeof(int));
    int*   blk_off   = (int*)  alloc(64 * sizeof(int));
    int2*  csr       = (int2*) alloc((size_t)N_EDGES * sizeof(int2));
    float* bufA      = (float*)alloc((size_t)N_NODES * F_HID * sizeof(float));
    float* bufB      = (float*)alloc((size_t)N_NODES * F_HID * sizeof(float));

    const int NSCAN = (N_NODES + 1023) / 1024;   // 49 (<=64 for 1-wave phase 2)

    // --- CSR build ---
    hipMemsetAsync(counts, 0, N_NODES * sizeof(int), stream);
    count_kernel<<<(N_EDGES + 255) / 256, 256, 0, stream>>>(dst, counts, N_EDGES);
    scan_local_kernel<<<NSCAN, 1024, 0, stream>>>(counts, row_start, dinv, blk_sums, N_NODES);
    scan_blk_kernel<<<1, 64, 0, stream>>>(blk_sums, blk_off, row_start, N_NODES, NSCAN);
    scan_apply_kernel<<<NSCAN, 1024, 0, stream>>>(row_start, cursor, blk_off, N_NODES);
    fill_csr_kernel<<<(N_EDGES + 255) / 256, 256, 0, stream>>>(
        src, dst, cursor, dinv, csr, N_EDGES);

    // --- Layer 1 ---
    gemm96_kernel<F_INN><<<(N_NODES + 63) / 64, dim3(24, 16), 0, stream>>>(
        x, W1, bufA, N_NODES);
    agg_kernel<<<(N_NODES + 3) / 4, 256, 0, stream>>>(
        bufA, row_start, csr, dinv, b1, bufB, N_NODES);

    // --- Layer 2 ---
    gemm96_kernel<F_HID><<<(N_NODES + 63) / 64, dim3(24, 16), 0, stream>>>(
        bufB, W2, bufA, N_NODES);
    agg_kernel<<<(N_NODES + 3) / 4, 256, 0, stream>>>(
        bufA, row_start, csr, dinv, b2, bufB, N_NODES);

    // --- Output ---
    gemm_out_kernel<<<(N_NODES + 31) / 32, dim3(10, 32), 0, stream>>>(
        bufB, Wout, bout, out, N_NODES);
}

// Round 3
// 271.669 us; speedup vs baseline: 2.6009x; 1.2114x over previous
//
#include <hip/hip_runtime.h>
#include <hip/hip_fp16.h>

#define N_NODES 50000
#define N_EDGES 800000
#define F_INN   128
#define F_HID   96
#define F_OUTT  40

// ---------------------------------------------------------------------------
// CSR build: count(+rank) -> 3-phase parallel scan (+dinv) -> atomic-free fill
// ---------------------------------------------------------------------------

// counts[dst]++ ; rank[i] = this edge's slot within its dst row (atomic return).
__global__ void count_kernel(const int* __restrict__ dst, int* __restrict__ counts,
                             int* __restrict__ rank, int e) {
    int i = blockIdx.x * blockDim.x + threadIdx.x;
    if (i < e) rank[i] = atomicAdd(&counts[dst[i]], 1);
}

// Phase 1: per-block (1024-wide) exclusive scan; write local scan + dinv + block sum.
__global__ __launch_bounds__(1024) void scan_local_kernel(
        const int* __restrict__ counts, int* __restrict__ row_start,
        float* __restrict__ dinv, int* __restrict__ blk_sums, int n) {
    __shared__ int wave_sums[16];
    int tid = threadIdx.x, lane = tid & 63, wid = tid >> 6;
    int i = blockIdx.x * 1024 + tid;
    int v = (i < n) ? counts[i] : 0;
    int val = v;
    #pragma unroll
    for (int off = 1; off < 64; off <<= 1) {
        int u = __shfl_up(val, off, 64);
        if (lane >= off) val += u;
    }
    if (lane == 63) wave_sums[wid] = val;
    __syncthreads();
    if (wid == 0) {
        int w = (lane < 16) ? wave_sums[lane] : 0;
        #pragma unroll
        for (int off = 1; off < 16; off <<= 1) {
            int u = __shfl_up(w, off, 64);
            if (lane >= off) w += u;
        }
        if (lane < 16) wave_sums[lane] = w;   // inclusive wave totals
    }
    __syncthreads();
    int excl = ((wid == 0) ? 0 : wave_sums[wid - 1]) + (val - v);
    if (i < n) {
        row_start[i] = excl;                  // local (no global offset yet)
        dinv[i] = rsqrtf((float)(v + 1));     // +1 self loop
    }
    if (tid == 0) blk_sums[blockIdx.x] = wave_sums[15];
}

// Phase 2: one wave scans <=64 block sums -> exclusive offsets; writes total.
__global__ void scan_blk_kernel(const int* __restrict__ blk_sums, int* __restrict__ blk_off,
                                int* __restrict__ row_start, int n, int nblk) {
    int lane = threadIdx.x;
    int v = (lane < nblk) ? blk_sums[lane] : 0;
    int val = v;
    #pragma unroll
    for (int off = 1; off < 64; off <<= 1) {
        int u = __shfl_up(val, off, 64);
        if (lane >= off) val += u;
    }
    if (lane < nblk) blk_off[lane] = val - v;
    if (lane == 63) row_start[n] = val;       // == E
}

// Phase 3: add block offset.
__global__ __launch_bounds__(1024) void scan_apply_kernel(
        int* __restrict__ row_start, const int* __restrict__ blk_off, int n) {
    int i = blockIdx.x * 1024 + threadIdx.x;
    if (i < n) row_start[i] += blk_off[blockIdx.x];
}

// Atomic-free fill: pos = row_start[dst] + rank.  One scattered 4B store.
__global__ void fill_csr_kernel(const int* __restrict__ src, const int* __restrict__ dst,
                                const int* __restrict__ rank, const int* __restrict__ row_start,
                                int* __restrict__ csr_src, int e) {
    int i = blockIdx.x * blockDim.x + threadIdx.x;
    if (i >= e) return;
    csr_src[row_start[dst[i]] + rank[i]] = src[i];
}

// ---------------------------------------------------------------------------
// GEMM: T'[n][96] = dinv[n] * (A[n x FI] @ W[FI x 96]), stored fp16.
// blockDim (24,16): thread = 4 j x 4 nodes (strided 16). W in LDS.
// ---------------------------------------------------------------------------

template <int FI>
__global__ __launch_bounds__(384) void gemm96_kernel(
        const float* __restrict__ A, const float* __restrict__ W,
        const float* __restrict__ dinv, __half2* __restrict__ C, int n) {
    __shared__ float Wlds[FI * 96];
    int tid = threadIdx.y * 24 + threadIdx.x;
    for (int i = tid; i < FI * 24; i += 384)
        reinterpret_cast<float4*>(Wlds)[i] = reinterpret_cast<const float4*>(W)[i];
    __syncthreads();

    int j  = threadIdx.x * 4;                 // 0..92
    int n0 = blockIdx.x * 64 + threadIdx.y;   // nodes n0, +16, +32, +48
    int nn[4];
    #pragma unroll
    for (int t = 0; t < 4; ++t) nn[t] = min(n0 + 16 * t, n - 1);

    float4 acc[4];
    #pragma unroll
    for (int t = 0; t < 4; ++t) acc[t] = make_float4(0.f, 0.f, 0.f, 0.f);

    for (int k = 0; k < FI; k += 4) {
        float4 a[4];
        #pragma unroll
        for (int t = 0; t < 4; ++t)
            a[t] = *reinterpret_cast<const float4*>(A + (size_t)nn[t] * FI + k);
        float4 w0 = *reinterpret_cast<const float4*>(Wlds + (k + 0) * 96 + j);
        float4 w1 = *reinterpret_cast<const float4*>(Wlds + (k + 1) * 96 + j);
        float4 w2 = *reinterpret_cast<const float4*>(Wlds + (k + 2) * 96 + j);
        float4 w3 = *reinterpret_cast<const float4*>(Wlds + (k + 3) * 96 + j);
        #pragma unroll
        for (int t = 0; t < 4; ++t) {
            acc[t].x += a[t].x * w0.x + a[t].y * w1.x + a[t].z * w2.x + a[t].w * w3.x;
            acc[t].y += a[t].x * w0.y + a[t].y * w1.y + a[t].z * w2.y + a[t].w * w3.y;
            acc[t].z += a[t].x * w0.z + a[t].y * w1.z + a[t].z * w2.z + a[t].w * w3.z;
            acc[t].w += a[t].x * w0.w + a[t].y * w1.w + a[t].z * w2.w + a[t].w * w3.w;
        }
    }
    #pragma unroll
    for (int t = 0; t < 4; ++t) {
        int node = n0 + 16 * t;
        if (node < n) {
            float dn = dinv[node];
            __half2 h01 = __floats2half2_rn(acc[t].x * dn, acc[t].y * dn);
            __half2 h23 = __floats2half2_rn(acc[t].z * dn, acc[t].w * dn);
            __half2* Cp = C + (size_t)node * 48 + (j >> 1);
            Cp[0] = h01;
            Cp[1] = h23;
        }
    }
}

// Output GEMM: out[n x 40] = A[n x 96] @ W[96 x 40] + bias. blockDim (10,32).
__global__ __launch_bounds__(320) void gemm_out_kernel(
        const float* __restrict__ A, const float* __restrict__ W,
        const float* __restrict__ bias, float* __restrict__ C, int n) {
    __shared__ float Wlds[96 * 40];
    int tid = threadIdx.y * 10 + threadIdx.x;
    for (int i = tid; i < 96 * 10; i += 320)
        reinterpret_cast<float4*>(Wlds)[i] = reinterpret_cast<const float4*>(W)[i];
    __syncthreads();

    int j    = threadIdx.x * 4;               // 0..36
    int node = blockIdx.x * 32 + threadIdx.y;
    int nc   = min(node, n - 1);
    float4 acc = make_float4(0.f, 0.f, 0.f, 0.f);
    for (int k = 0; k < 96; k += 4) {
        float4 a = *reinterpret_cast<const float4*>(A + (size_t)nc * 96 + k);
        float4 w0 = *reinterpret_cast<const float4*>(Wlds + (k + 0) * 40 + j);
        float4 w1 = *reinterpret_cast<const float4*>(Wlds + (k + 1) * 40 + j);
        float4 w2 = *reinterpret_cast<const float4*>(Wlds + (k + 2) * 40 + j);
        float4 w3 = *reinterpret_cast<const float4*>(Wlds + (k + 3) * 40 + j);
        acc.x += a.x * w0.x + a.y * w1.x + a.z * w2.x + a.w * w3.x;
        acc.y += a.x * w0.y + a.y * w1.y + a.z * w2.y + a.w * w3.y;
        acc.z += a.x * w0.z + a.y * w1.z + a.z * w2.z + a.w * w3.z;
        acc.w += a.x * w0.w + a.y * w1.w + a.z * w2.w + a.w * w3.w;
    }
    if (node < n) {
        float4 b = *reinterpret_cast<const float4*>(bias + j);
        acc.x += b.x; acc.y += b.y; acc.z += b.z; acc.w += b.w;
        *reinterpret_cast<float4*>(C + (size_t)node * 40 + j) = acc;
    }
}

// ---------------------------------------------------------------------------
// Aggregation: one WAVE per node, weightless row-sum over fp16 T'.
//   H[d] = relu( dinv[d] * (T'[d] + sum_{e} T'[src_e]) + b )
// Lanes 0..47 each hold one half2 of the 96-half row. Edge indices are
// wave-uniform -> scalar (s_load) traffic; gathers 4-deep in flight.
// ---------------------------------------------------------------------------

__global__ __launch_bounds__(256) void agg_kernel(
        const __half2* __restrict__ T, const int* __restrict__ row_start,
        const int* __restrict__ csr_src, const float* __restrict__ dinv,
        const float* __restrict__ bias, float* __restrict__ H, int n) {
    int lane = threadIdx.x & 63;
    int node = __builtin_amdgcn_readfirstlane(blockIdx.x * 4 + (threadIdx.x >> 6));
    if (node >= n) return;
    int fl = min(lane, 47);                    // lanes 48..63 duplicate lane 47

    float2 self = __half22float2(T[(size_t)node * 48 + fl]);
    float accx = self.x, accy = self.y;

    int idx = row_start[node];
    int end = row_start[node + 1];
    for (; idx + 4 <= end; idx += 4) {
        int s0 = csr_src[idx + 0];
        int s1 = csr_src[idx + 1];
        int s2 = csr_src[idx + 2];
        int s3 = csr_src[idx + 3];
        __half2 a0 = T[(size_t)s0 * 48 + fl];
        __half2 a1 = T[(size_t)s1 * 48 + fl];
        __half2 a2 = T[(size_t)s2 * 48 + fl];
        __half2 a3 = T[(size_t)s3 * 48 + fl];
        float2 f0 = __half22float2(a0);
        float2 f1 = __half22float2(a1);
        float2 f2 = __half22float2(a2);
        float2 f3 = __half22float2(a3);
        accx += f0.x + f1.x + f2.x + f3.x;
        accy += f0.y + f1.y + f2.y + f3.y;
    }
    for (; idx < end; ++idx) {
        float2 f = __half22float2(T[(size_t)csr_src[idx] * 48 + fl]);
        accx += f.x; accy += f.y;
    }
    if (lane < 48) {
        float dn = dinv[node];
        float2 b = reinterpret_cast<const float2*>(bias)[lane];
        float2 o;
        o.x = fmaxf(dn * accx + b.x, 0.f);
        o.y = fmaxf(dn * accy + b.y, 0.f);
        reinterpret_cast<float2*>(H)[(size_t)node * 48 + lane] = o;
    }
}

// ---------------------------------------------------------------------------

extern "C" void kernel_launch(void* const* d_in, const int* in_sizes, int n_in,
                              void* d_out, int out_size, void* d_ws, size_t ws_size,
                              hipStream_t stream) {
    const float* x    = (const float*)d_in[0];
    const int*   ei   = (const int*)d_in[1];
    const float* W1   = (const float*)d_in[2];
    const float* b1   = (const float*)d_in[3];
    const float* W2   = (const float*)d_in[4];
    const float* b2   = (const float*)d_in[5];
    const float* Wout = (const float*)d_in[6];
    const float* bout = (const float*)d_in[7];
    float*       out  = (float*)d_out;

    const int* src = ei;            // edge_index[0]
    const int* dst = ei + N_EDGES;  // edge_index[1]

    char* ws = (char*)d_ws;
    size_t off = 0;
    auto alloc = [&](size_t bytes) {
        size_t o = off;
        off = (off + bytes + 511) & ~(size_t)511;
        return (void*)(ws + o);
    };
    int*     counts    = (int*)    alloc(N_NODES * sizeof(int));
    int*     row_start = (int*)    alloc((N_NODES + 1) * sizeof(int));
    float*   dinv      = (float*)  alloc(N_NODES * sizeof(float));
    int*     blk_sums  = (int*)    alloc(64 * sizeof(int));
    int*     blk_off   = (int*)    alloc(64 * sizeof(int));
    int*     rank      = (int*)    alloc((size_t)N_EDGES * sizeof(int));
    int*     csr_src   = (int*)    alloc((size_t)N_EDGES * sizeof(int));
    __half2* Th        = (__half2*)alloc((size_t)N_NODES * 48 * sizeof(__half2));
    float*   Hf        = (float*)  alloc((size_t)N_NODES * F_HID * sizeof(float));

    const int NSCAN = (N_NODES + 1023) / 1024;   // 49 (<=64 for 1-wave phase 2)

    // --- CSR build (topology only, reused by both layers) ---
    hipMemsetAsync(counts, 0, N_NODES * sizeof(int), stream);
    count_kernel<<<(N_EDGES + 255) / 256, 256, 0, stream>>>(dst, counts, rank, N_EDGES);
    scan_local_kernel<<<NSCAN, 1024, 0, stream>>>(counts, row_start, dinv, blk_sums, N_NODES);
    scan_blk_kernel<<<1, 64, 0, stream>>>(blk_sums, blk_off, row_start, N_NODES, NSCAN);
    scan_apply_kernel<<<NSCAN, 1024, 0, stream>>>(row_start, blk_off, N_NODES);
    fill_csr_kernel<<<(N_EDGES + 255) / 256, 256, 0, stream>>>(
        src, dst, rank, row_start, csr_src, N_EDGES);

    // --- Layer 1: T' = dinv * (x @ W1); H = relu(dinv * (T'self + sum T'src) + b1) ---
    gemm96_kernel<F_INN><<<(N_NODES + 63) / 64, dim3(24, 16), 0, stream>>>(
        x, W1, dinv, Th, N_NODES);
    agg_kernel<<<(N_NODES + 3) / 4, 256, 0, stream>>>(
        Th, row_start, csr_src, dinv, b1, Hf, N_NODES);

    // --- Layer 2 ---
    gemm96_kernel<F_HID><<<(N_NODES + 63) / 64, dim3(24, 16), 0, stream>>>(
        Hf, W2, dinv, Th, N_NODES);
    agg_kernel<<<(N_NODES + 3) / 4, 256, 0, stream>>>(
        Th, row_start, csr_src, dinv, b2, Hf, N_NODES);

    // --- Output ---
    gemm_out_kernel<<<(N_NODES + 31) / 32, dim3(10, 32), 0, stream>>>(
        Hf, Wout, bout, out, N_NODES);
}